// Round 3
// baseline (1271.763 us; speedup 1.0000x reference)
//
#include <hip/hip_runtime.h>

// TransformerBlock on MI355X (gfx950). B=2 T=2048 D_MODEL=2048 H=16 HD=128 D_FF=5504.
// Round 3: dtype-robust. Device-side detection of fp32-vs-bf16 inputs, canonical
// bf16 conversion, all-bf16 MFMA pipeline, flag-selected output dtype.

using bf16 = __bf16;
typedef __bf16 bf16x8 __attribute__((ext_vector_type(8)));
typedef float f32x4 __attribute__((ext_vector_type(4)));

#define MFMA_BF16(a, b, c) __builtin_amdgcn_mfma_f32_16x16x32_bf16((a), (b), (c), 0, 0, 0)

// ---------------------------------------------------------------------------
// Detect input dtype from x's first 64 32-bit words. If data is bf16, both
// 16-bit halves have sane exponents (values ~N(0,1)); if fp32, the low half
// is random mantissa bits (sane-exponent prob ~0.24). flag=1 -> bf16 inputs.
// ---------------------------------------------------------------------------
__global__ void detect_dtype(const unsigned int* __restrict__ X, int* __restrict__ flag) {
  const int tid = threadIdx.x;  // 64 threads = 1 wave
  const unsigned int w = X[tid];
  const unsigned int e_lo = (w >> 7) & 0xFF;
  const unsigned int e_hi = (w >> 23) & 0xFF;
  const bool sane = (e_lo >= 97u && e_lo <= 157u) && (e_hi >= 97u && e_hi <= 157u);
  const unsigned long long m = __ballot(sane);
  if (tid == 0) *flag = (__popcll(m) > 48) ? 1 : 0;
}

// ---------------------------------------------------------------------------
// Canonicalize an input array to bf16. n must be a multiple of 2048.
// ---------------------------------------------------------------------------
__global__ __launch_bounds__(256) void convert_in(const void* __restrict__ src,
                                                  bf16* __restrict__ dst,
                                                  const int* __restrict__ flag) {
  const size_t i = ((size_t)blockIdx.x * 256 + threadIdx.x) * 8;
  if (*flag) {
    *(bf16x8*)(dst + i) = *(const bf16x8*)((const bf16*)src + i);
  } else {
    const float* s = (const float*)src;
    float4 a = *(const float4*)(s + i);
    float4 b = *(const float4*)(s + i + 4);
    bf16x8 o;
    o[0] = (bf16)a.x; o[1] = (bf16)a.y; o[2] = (bf16)a.z; o[3] = (bf16)a.w;
    o[4] = (bf16)b.x; o[5] = (bf16)b.y; o[6] = (bf16)b.z; o[7] = (bf16)b.w;
    *(bf16x8*)(dst + i) = o;
  }
}

// ---------------------------------------------------------------------------
// RMSNorm (bf16 in): one block per row of 2048, 256 threads x 8, fp32 math.
// ---------------------------------------------------------------------------
__global__ __launch_bounds__(256) void rmsnorm_bf16(const bf16* __restrict__ X,
                                                    const bf16* __restrict__ g,
                                                    bf16* __restrict__ Hout) {
  const int row = blockIdx.x, tid = threadIdx.x;
  const size_t off = (size_t)row * 2048 + tid * 8;
  bf16x8 x8 = *(const bf16x8*)(X + off);
  float v[8];
  float s = 0.f;
#pragma unroll
  for (int j = 0; j < 8; ++j) { v[j] = (float)x8[j]; s += v[j] * v[j]; }
#pragma unroll
  for (int o = 32; o; o >>= 1) s += __shfl_xor(s, o);
  __shared__ float red[4];
  if ((tid & 63) == 0) red[tid >> 6] = s;
  __syncthreads();
  const float tot = red[0] + red[1] + red[2] + red[3];
  const float inv = 1.f / (sqrtf(tot * (1.f / 2048.f)) + 1e-8f);
  bf16x8 g8 = *(const bf16x8*)(g + tid * 8);
  bf16x8 o8;
#pragma unroll
  for (int j = 0; j < 8; ++j) o8[j] = (bf16)((float)g8[j] * v[j] * inv);
  *(bf16x8*)(Hout + off) = o8;
}

// RMSNorm (fp32 in) for the second norm over the fp32 residual x1.
__global__ __launch_bounds__(256) void rmsnorm_f32(const float* __restrict__ X,
                                                   const bf16* __restrict__ g,
                                                   bf16* __restrict__ Hout) {
  const int row = blockIdx.x, tid = threadIdx.x;
  const size_t off = (size_t)row * 2048 + tid * 8;
  float4 a0 = *(const float4*)(X + off);
  float4 a1 = *(const float4*)(X + off + 4);
  float v[8] = {a0.x, a0.y, a0.z, a0.w, a1.x, a1.y, a1.z, a1.w};
  float s = 0.f;
#pragma unroll
  for (int j = 0; j < 8; ++j) s += v[j] * v[j];
#pragma unroll
  for (int o = 32; o; o >>= 1) s += __shfl_xor(s, o);
  __shared__ float red[4];
  if ((tid & 63) == 0) red[tid >> 6] = s;
  __syncthreads();
  const float tot = red[0] + red[1] + red[2] + red[3];
  const float inv = 1.f / (sqrtf(tot * (1.f / 2048.f)) + 1e-8f);
  bf16x8 g8 = *(const bf16x8*)(g + tid * 8);
  bf16x8 o8;
#pragma unroll
  for (int j = 0; j < 8; ++j) o8[j] = (bf16)((float)g8[j] * v[j] * inv);
  *(bf16x8*)(Hout + off) = o8;
}

// ---------------------------------------------------------------------------
// RoPE in-place on Q and K. Each thread owns a (d, d+64) partner pair.
// ---------------------------------------------------------------------------
__global__ __launch_bounds__(256) void rope_k(bf16* __restrict__ Q, bf16* __restrict__ Kg,
                                              const bf16* __restrict__ cosb,
                                              const bf16* __restrict__ sinb) {
  const int tid = threadIdx.x;
  const int rr = tid >> 7;
  const int c = tid & 127;
  const int bt = blockIdx.x * 2 + rr;
  const int t = bt & 2047;
  const int h = c >> 3;
  const int d0 = (c & 7) * 8;
  const size_t row = (size_t)bt * 2048;
  const int i0 = h * 128 + d0;
  bf16x8 c0 = *(const bf16x8*)(cosb + t * 128 + d0);
  bf16x8 c1 = *(const bf16x8*)(cosb + t * 128 + d0 + 64);
  bf16x8 s0 = *(const bf16x8*)(sinb + t * 128 + d0);
  bf16x8 s1 = *(const bf16x8*)(sinb + t * 128 + d0 + 64);
  bf16x8 qa = *(const bf16x8*)(Q + row + i0);
  bf16x8 qb = *(const bf16x8*)(Q + row + i0 + 64);
  bf16x8 ka = *(const bf16x8*)(Kg + row + i0);
  bf16x8 kb = *(const bf16x8*)(Kg + row + i0 + 64);
  bf16x8 qo0, qo1, ko0, ko1;
#pragma unroll
  for (int j = 0; j < 8; ++j) {
    float cj0 = (float)c0[j], cj1 = (float)c1[j];
    float sj0 = (float)s0[j], sj1 = (float)s1[j];
    float qaj = (float)qa[j], qbj = (float)qb[j];
    float kaj = (float)ka[j], kbj = (float)kb[j];
    qo0[j] = (bf16)(qaj * cj0 - qbj * sj0);
    qo1[j] = (bf16)(qbj * cj1 + qaj * sj1);
    ko0[j] = (bf16)(kaj * cj0 - kbj * sj0);
    ko1[j] = (bf16)(kbj * cj1 + kaj * sj1);
  }
  *(bf16x8*)(Q + row + i0) = qo0;
  *(bf16x8*)(Q + row + i0 + 64) = qo1;
  *(bf16x8*)(Kg + row + i0) = ko0;
  *(bf16x8*)(Kg + row + i0 + 64) = ko1;
}

// ---------------------------------------------------------------------------
// GEMM C = A(MxK) * W(NxK)^T, bf16 MFMA 16x16x32, 128x128 tile, 4 waves 2x2.
// Synchronous staging. EPI: 0 bf16; 1 fp32 = v + bf16 res; 2 silu->bf16;
// 3 v*mulb->bf16; 4 fp32 res + v -> d_out (dtype per oflag).
// ---------------------------------------------------------------------------
template <int EPI>
__global__ __launch_bounds__(256) void gemm_bt(const bf16* __restrict__ A,
                                               const bf16* __restrict__ W,
                                               bf16* __restrict__ Cb, float* __restrict__ Cf,
                                               const bf16* __restrict__ resb,
                                               const float* __restrict__ resf,
                                               const bf16* __restrict__ mulb,
                                               const int* __restrict__ oflag,
                                               int M, int N, int K) {
  __shared__ bf16 As[128 * 32];
  __shared__ bf16 Ws[128 * 32];
  const int tid = threadIdx.x;
  const int wave = tid >> 6, lane = tid & 63;
  const int quad = lane >> 4, l15 = lane & 15;
  const int wm = wave >> 1, wn = wave & 1;
  const int m0 = blockIdx.y * 128, n0 = blockIdx.x * 128;

  f32x4 acc[4][4];
#pragma unroll
  for (int i = 0; i < 4; ++i)
#pragma unroll
    for (int j = 0; j < 4; ++j) acc[i][j] = {0.f, 0.f, 0.f, 0.f};

  const bf16* Ab = A + (size_t)m0 * K;
  const bf16* Wb = W + (size_t)n0 * K;

  const int nk = K >> 5;
  for (int kb = 0; kb < nk; ++kb) {
    const int k0 = kb << 5;
    __syncthreads();
    bf16x8 av[2], wv[2];
#pragma unroll
    for (int c = 0; c < 2; ++c) {
      const int ch = tid + 256 * c;
      const int row = ch >> 2;
      const int kc = (ch & 3) * 8;
      av[c] = *(const bf16x8*)(Ab + (size_t)row * K + k0 + kc);
      wv[c] = *(const bf16x8*)(Wb + (size_t)row * K + k0 + kc);
    }
#pragma unroll
    for (int c = 0; c < 2; ++c) {
      const int ch = tid + 256 * c;
      const int row = ch >> 2;
      const int kc = (ch & 3) * 8;
      *(bf16x8*)&As[row * 32 + kc] = av[c];
      *(bf16x8*)&Ws[row * 32 + kc] = wv[c];
    }
    __syncthreads();
    bf16x8 af[4], wf[4];
#pragma unroll
    for (int mt = 0; mt < 4; ++mt)
      af[mt] = *(const bf16x8*)&As[(wm * 64 + mt * 16 + l15) * 32 + quad * 8];
#pragma unroll
    for (int nt = 0; nt < 4; ++nt)
      wf[nt] = *(const bf16x8*)&Ws[(wn * 64 + nt * 16 + l15) * 32 + quad * 8];
#pragma unroll
    for (int mt = 0; mt < 4; ++mt)
#pragma unroll
      for (int nt = 0; nt < 4; ++nt)
        acc[mt][nt] = MFMA_BF16(af[mt], wf[nt], acc[mt][nt]);
  }

  const int obf = (EPI == 4 && oflag) ? *oflag : 0;
#pragma unroll
  for (int mt = 0; mt < 4; ++mt) {
#pragma unroll
    for (int nt = 0; nt < 4; ++nt) {
#pragma unroll
      for (int r = 0; r < 4; ++r) {
        const int row = m0 + wm * 64 + mt * 16 + quad * 4 + r;
        const int col = n0 + wn * 64 + nt * 16 + l15;
        const size_t idx = (size_t)row * N + col;
        const float v = acc[mt][nt][r];
        if constexpr (EPI == 0) {
          Cb[idx] = (bf16)v;
        } else if constexpr (EPI == 1) {
          Cf[idx] = v + (float)resb[idx];
        } else if constexpr (EPI == 2) {
          Cb[idx] = (bf16)(v / (1.f + __expf(-v)));   // silu
        } else if constexpr (EPI == 3) {
          Cb[idx] = (bf16)((float)mulb[idx] * v);
        } else {  // EPI == 4: final output, dtype per flag
          const float rres = resf[idx] + v;
          if (obf) Cb[idx] = (bf16)rres;
          else     Cf[idx] = rres;
        }
      }
    }
  }
}

// ---------------------------------------------------------------------------
// Flash attention (causal). Grid (T/64, B*H). Wave owns 16 queries.
// ---------------------------------------------------------------------------
__global__ __launch_bounds__(256) void flash_attn(const bf16* __restrict__ Q,
                                                  const bf16* __restrict__ Kg,
                                                  const bf16* __restrict__ Vg,
                                                  bf16* __restrict__ O) {
  __shared__ bf16 Ks[64 * 128];    // [key][dim]
  __shared__ bf16 Vt[128 * 64];    // [dim][key]
  __shared__ bf16 Ps[4 * 16 * 64]; // per-wave [q_local][key_local]
  const int tid = threadIdx.x;
  const int wave = tid >> 6, lane = tid & 63;
  const int quad = lane >> 4, l15 = lane & 15;
  const int qi = blockIdx.x;
  const int bh = blockIdx.y;
  const int b = bh >> 4, h = bh & 15;
  const size_t base = (size_t)b * 2048 * 2048 + h * 128;
  const int q0 = qi * 64;

  bf16x8 qf[4];
  {
    const bf16* qrow = Q + base + (size_t)(q0 + wave * 16 + l15) * 2048;
#pragma unroll
    for (int ks = 0; ks < 4; ++ks) qf[ks] = *(const bf16x8*)(qrow + ks * 32 + quad * 8);
  }

  f32x4 o[8];
#pragma unroll
  for (int i = 0; i < 8; ++i) o[i] = {0.f, 0.f, 0.f, 0.f};
  float m_r[4] = {-1e30f, -1e30f, -1e30f, -1e30f};
  float l_r[4] = {0.f, 0.f, 0.f, 0.f};

  const float scale = 0.08838834764831845f; // 1/sqrt(128)
  const int nkb = qi + 1;

  for (int kb = 0; kb < nkb; ++kb) {
    const int k0 = kb * 64;
    __syncthreads();
#pragma unroll
    for (int c = 0; c < 4; ++c) {
      const int ch = tid + 256 * c;
      const int row = ch >> 4;
      const int dd = (ch & 15) * 8;
      *(bf16x8*)&Ks[row * 128 + dd] =
          *(const bf16x8*)(Kg + base + (size_t)(k0 + row) * 2048 + dd);
    }
#pragma unroll
    for (int c = 0; c < 4; ++c) {
      const int tau = tid + 256 * c;
      const int key = tau & 63;
      const int d0 = (tau >> 6) * 8;
      bf16x8 v8 = *(const bf16x8*)(Vg + base + (size_t)(k0 + key) * 2048 + d0);
#pragma unroll
      for (int j = 0; j < 8; ++j) Vt[(d0 + j) * 64 + key] = v8[j];
    }
    __syncthreads();

    f32x4 s[4];
#pragma unroll
    for (int nt = 0; nt < 4; ++nt) {
      s[nt] = {0.f, 0.f, 0.f, 0.f};
#pragma unroll
      for (int ks = 0; ks < 4; ++ks) {
        bf16x8 kf = *(const bf16x8*)&Ks[(nt * 16 + l15) * 128 + ks * 32 + quad * 8];
        s[nt] = MFMA_BF16(qf[ks], kf, s[nt]);
      }
    }

    float sv[4][4];
#pragma unroll
    for (int nt = 0; nt < 4; ++nt) {
#pragma unroll
      for (int r = 0; r < 4; ++r) {
        float v = s[nt][r] * scale;
        const int key = k0 + nt * 16 + l15;
        const int qq = q0 + wave * 16 + quad * 4 + r;
        if (key > qq) v = -1e9f;
        sv[nt][r] = v;
      }
    }

#pragma unroll
    for (int r = 0; r < 4; ++r) {
      float rmax = fmaxf(fmaxf(sv[0][r], sv[1][r]), fmaxf(sv[2][r], sv[3][r]));
#pragma unroll
      for (int off = 1; off < 16; off <<= 1) rmax = fmaxf(rmax, __shfl_xor(rmax, off));
      const float mnew = fmaxf(m_r[r], rmax);
      const float alpha = __expf(m_r[r] - mnew);
      float psum = 0.f;
#pragma unroll
      for (int nt = 0; nt < 4; ++nt) {
        const float p = __expf(sv[nt][r] - mnew);
        psum += p;
        Ps[wave * 1024 + (quad * 4 + r) * 64 + nt * 16 + l15] = (bf16)p;
      }
#pragma unroll
      for (int off = 1; off < 16; off <<= 1) psum += __shfl_xor(psum, off);
      l_r[r] = l_r[r] * alpha + psum;
      m_r[r] = mnew;
#pragma unroll
      for (int nt2 = 0; nt2 < 8; ++nt2) o[nt2][r] *= alpha;
    }

    asm volatile("s_waitcnt lgkmcnt(0)" ::: "memory");

#pragma unroll
    for (int ks2 = 0; ks2 < 2; ++ks2) {
      bf16x8 pf = *(const bf16x8*)&Ps[wave * 1024 + l15 * 64 + ks2 * 32 + quad * 8];
#pragma unroll
      for (int nt2 = 0; nt2 < 8; ++nt2) {
        bf16x8 vf = *(const bf16x8*)&Vt[(nt2 * 16 + l15) * 64 + ks2 * 32 + quad * 8];
        o[nt2] = MFMA_BF16(pf, vf, o[nt2]);
      }
    }
  }

#pragma unroll
  for (int nt2 = 0; nt2 < 8; ++nt2) {
#pragma unroll
    for (int r = 0; r < 4; ++r) {
      const int qq = q0 + wave * 16 + quad * 4 + r;
      const int dd = nt2 * 16 + l15;
      O[base + (size_t)qq * 2048 + dd] = (bf16)(o[nt2][r] / l_r[r]);
    }
  }
}

// ---------------------------------------------------------------------------
extern "C" void kernel_launch(void* const* d_in, const int* in_sizes, int n_in,
                              void* d_out, int out_size, void* d_ws, size_t ws_size,
                              hipStream_t stream) {
  const void* x_raw = d_in[0];
  const void* cos_raw = d_in[1];
  const void* sin_raw = d_in[2];
  // d_in[3] = mask — causal, applied analytically in flash_attn
  const void* g1_raw = d_in[4];
  const void* g2_raw = d_in[5];
  const void* W_raw[7] = {d_in[6], d_in[7], d_in[8], d_in[9], d_in[10], d_in[11], d_in[12]};
  // sizes:   Wq,Wk,Wv,Wo = 2048*2048; W1,W2 = 5504*2048; Wout = 2048*5504

  char* ws = (char*)d_ws;
  const size_t MB = 1048576ull;
  int* flag = (int*)ws;
  bf16* g1c = (bf16*)(ws + 4096);
  bf16* g2c = (bf16*)(ws + 12288);
  bf16* cosc = (bf16*)(ws + 65536);          // 512KB
  bf16* sinc = (bf16*)(ws + 655360);         // 512KB
  bf16* xc   = (bf16*)(ws + 2 * MB);         // 16MB  [2,18)
  bf16* wslot= (bf16*)(ws + 18 * MB);        // 23MB  [18,41)
  bf16* hbuf = (bf16*)(ws + 41 * MB);        // 16MB  [41,57)
  bf16* qbuf = (bf16*)(ws + 57 * MB);        // 16MB  [57,73)
  bf16* kbuf = (bf16*)(ws + 73 * MB);        // 16MB  [73,89)
  bf16* vbuf = (bf16*)(ws + 89 * MB);        // 16MB  [89,105)
  bf16* abuf = (bf16*)(ws + 105 * MB);       // 16MB  [105,121)
  float* x1  = (float*)(ws + 57 * MB);       // 32MB over q,k (dead after flash)
  bf16* h2   = (bf16*)(ws + 41 * MB);        // over h (dead after V gemm)
  bf16* ubuf = (bf16*)(ws + 89 * MB);        // 43MB over v,attn [89,132)

  const int M = 4096; // B*T
  dim3 blk(256);

  detect_dtype<<<1, 64, 0, stream>>>((const unsigned int*)x_raw, flag);

  convert_in<<<4096, blk, 0, stream>>>(x_raw, xc, flag);       // 8.39M
  convert_in<<<128, blk, 0, stream>>>(cos_raw, cosc, flag);    // 262144
  convert_in<<<128, blk, 0, stream>>>(sin_raw, sinc, flag);    // 262144
  convert_in<<<1, blk, 0, stream>>>(g1_raw, g1c, flag);        // 2048
  convert_in<<<1, blk, 0, stream>>>(g2_raw, g2c, flag);        // 2048

  rmsnorm_bf16<<<M, blk, 0, stream>>>(xc, g1c, hbuf);

  // Q = h Wq^T
  convert_in<<<2048, blk, 0, stream>>>(W_raw[0], wslot, flag);
  gemm_bt<0><<<dim3(16, 32), blk, 0, stream>>>(hbuf, wslot, qbuf, nullptr, nullptr, nullptr, nullptr, nullptr, M, 2048, 2048);
  // K = h Wk^T
  convert_in<<<2048, blk, 0, stream>>>(W_raw[1], wslot, flag);
  gemm_bt<0><<<dim3(16, 32), blk, 0, stream>>>(hbuf, wslot, kbuf, nullptr, nullptr, nullptr, nullptr, nullptr, M, 2048, 2048);
  // V = h Wv^T
  convert_in<<<2048, blk, 0, stream>>>(W_raw[2], wslot, flag);
  gemm_bt<0><<<dim3(16, 32), blk, 0, stream>>>(hbuf, wslot, vbuf, nullptr, nullptr, nullptr, nullptr, nullptr, M, 2048, 2048);

  rope_k<<<M / 2, blk, 0, stream>>>(qbuf, kbuf, cosc, sinc);
  flash_attn<<<dim3(32, 32), blk, 0, stream>>>(qbuf, kbuf, vbuf, abuf);

  // x1 = x + attn Wo^T  (fp32)
  convert_in<<<2048, blk, 0, stream>>>(W_raw[3], wslot, flag);
  gemm_bt<1><<<dim3(16, 32), blk, 0, stream>>>(abuf, wslot, nullptr, x1, xc, nullptr, nullptr, nullptr, M, 2048, 2048);

  rmsnorm_f32<<<M, blk, 0, stream>>>(x1, g2c, h2);

  // u = silu(h2 W1^T)
  convert_in<<<5504, blk, 0, stream>>>(W_raw[4], wslot, flag);
  gemm_bt<2><<<dim3(43, 32), blk, 0, stream>>>(h2, wslot, ubuf, nullptr, nullptr, nullptr, nullptr, nullptr, M, 5504, 2048);
  // u = u * (h2 W2^T)
  convert_in<<<5504, blk, 0, stream>>>(W_raw[5], wslot, flag);
  gemm_bt<3><<<dim3(43, 32), blk, 0, stream>>>(h2, wslot, ubuf, nullptr, nullptr, nullptr, ubuf, nullptr, M, 5504, 2048);
  // out = x1 + u Wout^T  (dtype per flag)
  convert_in<<<5504, blk, 0, stream>>>(W_raw[6], wslot, flag);
  gemm_bt<4><<<dim3(16, 32), blk, 0, stream>>>(ubuf, wslot, (bf16*)d_out, (float*)d_out, nullptr, x1, nullptr, flag, M, 2048, 5504);
}

// Round 4
// 1119.396 us; speedup vs baseline: 1.1361x; 1.1361x over previous
//
#include <hip/hip_runtime.h>

// TransformerBlock on MI355X (gfx950). B=2 T=2048 D_MODEL=2048 H=16 HD=128 D_FF=5504.
// Round 4: fp32 inputs confirmed (detect/convert kept). Flash: padded LDS (no bank
// conflicts) + paired q-tiles (load balance). GEMM: async global_load_lds staging.

using bf16 = __bf16;
typedef __bf16 bf16x2 __attribute__((ext_vector_type(2)));
typedef __bf16 bf16x8 __attribute__((ext_vector_type(8)));
typedef float f32x4 __attribute__((ext_vector_type(4)));

#define MFMA_BF16(a, b, c) __builtin_amdgcn_mfma_f32_16x16x32_bf16((a), (b), (c), 0, 0, 0)

__device__ __forceinline__ void gld_lds16(const void* g, void* l) {
  // async global->LDS; each lane supplies its global addr, LDS dst = wave-uniform
  // base + lane*16 (HW rule). 16B width => global_load_lds_dwordx4.
  __builtin_amdgcn_global_load_lds((const __attribute__((address_space(1))) void*)g,
                                   (__attribute__((address_space(3))) void*)l,
                                   16, 0, 0);
}

// ---------------------------------------------------------------------------
// Detect input dtype (fp32 vs bf16) from x's first 64 words. flag=1 -> bf16.
// ---------------------------------------------------------------------------
__global__ void detect_dtype(const unsigned int* __restrict__ X, int* __restrict__ flag) {
  const int tid = threadIdx.x;  // 64 threads = 1 wave
  const unsigned int w = X[tid];
  const unsigned int e_lo = (w >> 7) & 0xFF;
  const unsigned int e_hi = (w >> 23) & 0xFF;
  const bool sane = (e_lo >= 97u && e_lo <= 157u) && (e_hi >= 97u && e_hi <= 157u);
  const unsigned long long m = __ballot(sane);
  if (tid == 0) *flag = (__popcll(m) > 48) ? 1 : 0;
}

__global__ __launch_bounds__(256) void convert_in(const void* __restrict__ src,
                                                  bf16* __restrict__ dst,
                                                  const int* __restrict__ flag) {
  const size_t i = ((size_t)blockIdx.x * 256 + threadIdx.x) * 8;
  if (*flag) {
    *(bf16x8*)(dst + i) = *(const bf16x8*)((const bf16*)src + i);
  } else {
    const float* s = (const float*)src;
    float4 a = *(const float4*)(s + i);
    float4 b = *(const float4*)(s + i + 4);
    bf16x8 o;
    o[0] = (bf16)a.x; o[1] = (bf16)a.y; o[2] = (bf16)a.z; o[3] = (bf16)a.w;
    o[4] = (bf16)b.x; o[5] = (bf16)b.y; o[6] = (bf16)b.z; o[7] = (bf16)b.w;
    *(bf16x8*)(dst + i) = o;
  }
}

// ---------------------------------------------------------------------------
// RMSNorm kernels (fp32 math).
// ---------------------------------------------------------------------------
__global__ __launch_bounds__(256) void rmsnorm_bf16(const bf16* __restrict__ X,
                                                    const bf16* __restrict__ g,
                                                    bf16* __restrict__ Hout) {
  const int row = blockIdx.x, tid = threadIdx.x;
  const size_t off = (size_t)row * 2048 + tid * 8;
  bf16x8 x8 = *(const bf16x8*)(X + off);
  float v[8];
  float s = 0.f;
#pragma unroll
  for (int j = 0; j < 8; ++j) { v[j] = (float)x8[j]; s += v[j] * v[j]; }
#pragma unroll
  for (int o = 32; o; o >>= 1) s += __shfl_xor(s, o);
  __shared__ float red[4];
  if ((tid & 63) == 0) red[tid >> 6] = s;
  __syncthreads();
  const float tot = red[0] + red[1] + red[2] + red[3];
  const float inv = 1.f / (sqrtf(tot * (1.f / 2048.f)) + 1e-8f);
  bf16x8 g8 = *(const bf16x8*)(g + tid * 8);
  bf16x8 o8;
#pragma unroll
  for (int j = 0; j < 8; ++j) o8[j] = (bf16)((float)g8[j] * v[j] * inv);
  *(bf16x8*)(Hout + off) = o8;
}

__global__ __launch_bounds__(256) void rmsnorm_f32(const float* __restrict__ X,
                                                   const bf16* __restrict__ g,
                                                   bf16* __restrict__ Hout) {
  const int row = blockIdx.x, tid = threadIdx.x;
  const size_t off = (size_t)row * 2048 + tid * 8;
  float4 a0 = *(const float4*)(X + off);
  float4 a1 = *(const float4*)(X + off + 4);
  float v[8] = {a0.x, a0.y, a0.z, a0.w, a1.x, a1.y, a1.z, a1.w};
  float s = 0.f;
#pragma unroll
  for (int j = 0; j < 8; ++j) s += v[j] * v[j];
#pragma unroll
  for (int o = 32; o; o >>= 1) s += __shfl_xor(s, o);
  __shared__ float red[4];
  if ((tid & 63) == 0) red[tid >> 6] = s;
  __syncthreads();
  const float tot = red[0] + red[1] + red[2] + red[3];
  const float inv = 1.f / (sqrtf(tot * (1.f / 2048.f)) + 1e-8f);
  bf16x8 g8 = *(const bf16x8*)(g + tid * 8);
  bf16x8 o8;
#pragma unroll
  for (int j = 0; j < 8; ++j) o8[j] = (bf16)((float)g8[j] * v[j] * inv);
  *(bf16x8*)(Hout + off) = o8;
}

// ---------------------------------------------------------------------------
// RoPE in-place on Q and K.
// ---------------------------------------------------------------------------
__global__ __launch_bounds__(256) void rope_k(bf16* __restrict__ Q, bf16* __restrict__ Kg,
                                              const bf16* __restrict__ cosb,
                                              const bf16* __restrict__ sinb) {
  const int tid = threadIdx.x;
  const int rr = tid >> 7;
  const int c = tid & 127;
  const int bt = blockIdx.x * 2 + rr;
  const int t = bt & 2047;
  const int h = c >> 3;
  const int d0 = (c & 7) * 8;
  const size_t row = (size_t)bt * 2048;
  const int i0 = h * 128 + d0;
  bf16x8 c0 = *(const bf16x8*)(cosb + t * 128 + d0);
  bf16x8 c1 = *(const bf16x8*)(cosb + t * 128 + d0 + 64);
  bf16x8 s0 = *(const bf16x8*)(sinb + t * 128 + d0);
  bf16x8 s1 = *(const bf16x8*)(sinb + t * 128 + d0 + 64);
  bf16x8 qa = *(const bf16x8*)(Q + row + i0);
  bf16x8 qb = *(const bf16x8*)(Q + row + i0 + 64);
  bf16x8 ka = *(const bf16x8*)(Kg + row + i0);
  bf16x8 kb = *(const bf16x8*)(Kg + row + i0 + 64);
  bf16x8 qo0, qo1, ko0, ko1;
#pragma unroll
  for (int j = 0; j < 8; ++j) {
    float cj0 = (float)c0[j], cj1 = (float)c1[j];
    float sj0 = (float)s0[j], sj1 = (float)s1[j];
    float qaj = (float)qa[j], qbj = (float)qb[j];
    float kaj = (float)ka[j], kbj = (float)kb[j];
    qo0[j] = (bf16)(qaj * cj0 - qbj * sj0);
    qo1[j] = (bf16)(qbj * cj1 + qaj * sj1);
    ko0[j] = (bf16)(kaj * cj0 - kbj * sj0);
    ko1[j] = (bf16)(kbj * cj1 + kaj * sj1);
  }
  *(bf16x8*)(Q + row + i0) = qo0;
  *(bf16x8*)(Q + row + i0 + 64) = qo1;
  *(bf16x8*)(Kg + row + i0) = ko0;
  *(bf16x8*)(Kg + row + i0 + 64) = ko1;
}

// ---------------------------------------------------------------------------
// GEMM C = A(MxK) * W(NxK)^T, bf16 MFMA 16x16x32, 128x128 tile, 4 waves 2x2.
// m97-style async staging: global_load_lds width 16.
// EPI: 0 bf16; 1 fp32 = v + bf16 res; 2 silu->bf16; 3 v*mulb->bf16;
//      4 fp32 res + v -> d_out (dtype per oflag).
// ---------------------------------------------------------------------------
template <int EPI>
__global__ __launch_bounds__(256) void gemm_bt(const bf16* __restrict__ A,
                                               const bf16* __restrict__ W,
                                               bf16* __restrict__ Cb, float* __restrict__ Cf,
                                               const bf16* __restrict__ resb,
                                               const float* __restrict__ resf,
                                               const bf16* __restrict__ mulb,
                                               const int* __restrict__ oflag,
                                               int M, int N, int K) {
  __shared__ bf16 As[128 * 32];
  __shared__ bf16 Ws[128 * 32];
  const int tid = threadIdx.x;
  const int wave = tid >> 6, lane = tid & 63;
  const int quad = lane >> 4, l15 = lane & 15;
  const int wm = wave >> 1, wn = wave & 1;
  const int m0 = blockIdx.y * 128, n0 = blockIdx.x * 128;

  f32x4 acc[4][4];
#pragma unroll
  for (int i = 0; i < 4; ++i)
#pragma unroll
    for (int j = 0; j < 4; ++j) acc[i][j] = {0.f, 0.f, 0.f, 0.f};

  const int srow = lane >> 2;       // 0..15
  const int skk = (lane & 3) * 8;   // 0,8,16,24
  const bf16* Ab = A + (size_t)m0 * K;
  const bf16* Wb = W + (size_t)n0 * K;

  const int nk = K >> 5;
  for (int kb = 0; kb < nk; ++kb) {
    const int k0 = kb << 5;
    __syncthreads();
#pragma unroll
    for (int c = 0; c < 2; ++c) {
      const int r = (wave * 2 + c) * 16 + srow;
      gld_lds16(Ab + (size_t)r * K + k0 + skk, (char*)As + (wave * 2 + c) * 1024);
      gld_lds16(Wb + (size_t)r * K + k0 + skk, (char*)Ws + (wave * 2 + c) * 1024);
    }
    __syncthreads();  // compiler drains vmcnt before s_barrier
    bf16x8 af[4], wf[4];
#pragma unroll
    for (int mt = 0; mt < 4; ++mt)
      af[mt] = *(const bf16x8*)&As[(wm * 64 + mt * 16 + l15) * 32 + quad * 8];
#pragma unroll
    for (int nt = 0; nt < 4; ++nt)
      wf[nt] = *(const bf16x8*)&Ws[(wn * 64 + nt * 16 + l15) * 32 + quad * 8];
#pragma unroll
    for (int mt = 0; mt < 4; ++mt)
#pragma unroll
      for (int nt = 0; nt < 4; ++nt)
        acc[mt][nt] = MFMA_BF16(af[mt], wf[nt], acc[mt][nt]);
  }

  const int obf = (EPI == 4 && oflag) ? *oflag : 0;
#pragma unroll
  for (int mt = 0; mt < 4; ++mt) {
#pragma unroll
    for (int nt = 0; nt < 4; ++nt) {
#pragma unroll
      for (int r = 0; r < 4; ++r) {
        const int row = m0 + wm * 64 + mt * 16 + quad * 4 + r;
        const int col = n0 + wn * 64 + nt * 16 + l15;
        const size_t idx = (size_t)row * N + col;
        const float v = acc[mt][nt][r];
        if constexpr (EPI == 0) {
          Cb[idx] = (bf16)v;
        } else if constexpr (EPI == 1) {
          Cf[idx] = v + (float)resb[idx];
        } else if constexpr (EPI == 2) {
          Cb[idx] = (bf16)(v / (1.f + __expf(-v)));   // silu
        } else if constexpr (EPI == 3) {
          Cb[idx] = (bf16)((float)mulb[idx] * v);
        } else {  // EPI == 4: final output, dtype per flag
          const float rres = resf[idx] + v;
          if (obf) Cb[idx] = (bf16)rres;
          else     Cf[idx] = rres;
        }
      }
    }
  }
}

// ---------------------------------------------------------------------------
// Flash attention (causal). Grid (16, B*H); block p handles q-tiles p and 31-p
// (33 K-tiles total -> perfectly balanced). Padded LDS rows kill bank conflicts:
// Ks stride 136, Vt/Ps stride 72 (all 16B-aligned; bank walk 4*l15 mod 32 = 2-way).
// ---------------------------------------------------------------------------
__global__ __launch_bounds__(256) void flash_attn(const bf16* __restrict__ Q,
                                                  const bf16* __restrict__ Kg,
                                                  const bf16* __restrict__ Vg,
                                                  bf16* __restrict__ O) {
  __shared__ bf16 Ks[64 * 136];     // [key][dim], padded
  __shared__ bf16 Vt[128 * 72];     // [dim][key], padded
  __shared__ bf16 Ps[4 * 16 * 72];  // per-wave [q_local][key], padded
  const int tid = threadIdx.x;
  const int wave = tid >> 6, lane = tid & 63;
  const int quad = lane >> 4, l15 = lane & 15;
  const int bh = blockIdx.y;
  const int b = bh >> 4, h = bh & 15;
  const size_t base = (size_t)b * 2048 * 2048 + h * 128;
  const float scale = 0.08838834764831845f;  // 1/sqrt(128)

#pragma unroll 1
  for (int half = 0; half < 2; ++half) {
    const int qt = half ? (31 - blockIdx.x) : blockIdx.x;
    const int q0 = qt * 64;

    bf16x8 qf[4];
    {
      const bf16* qrow = Q + base + (size_t)(q0 + wave * 16 + l15) * 2048;
#pragma unroll
      for (int ks = 0; ks < 4; ++ks) qf[ks] = *(const bf16x8*)(qrow + ks * 32 + quad * 8);
    }

    f32x4 o[8];
#pragma unroll
    for (int i = 0; i < 8; ++i) o[i] = {0.f, 0.f, 0.f, 0.f};
    float m_r[4] = {-1e30f, -1e30f, -1e30f, -1e30f};
    float l_r[4] = {0.f, 0.f, 0.f, 0.f};

    for (int kb = 0; kb <= qt; ++kb) {
      const int k0 = kb * 64;
      __syncthreads();
      // stage K tile [64][128] -> padded rows of 136
#pragma unroll
      for (int c = 0; c < 4; ++c) {
        const int ch = tid + 256 * c;
        const int row = ch >> 4;
        const int dd = (ch & 15) * 8;
        *(bf16x8*)&Ks[row * 136 + dd] =
            *(const bf16x8*)(Kg + base + (size_t)(k0 + row) * 2048 + dd);
      }
      // stage V transposed [128][64] -> padded rows of 72, key-pair b32 stores
#pragma unroll
      for (int c = 0; c < 2; ++c) {
        const int tau = tid + 256 * c;
        const int kp = tau & 31;          // key pair 0..31
        const int d0 = (tau >> 5) * 8;    // 0..120
        bf16x8 va = *(const bf16x8*)(Vg + base + (size_t)(k0 + 2 * kp) * 2048 + d0);
        bf16x8 vb = *(const bf16x8*)(Vg + base + (size_t)(k0 + 2 * kp + 1) * 2048 + d0);
#pragma unroll
        for (int j = 0; j < 8; ++j) {
          bf16x2 pr = {va[j], vb[j]};
          *(bf16x2*)&Vt[(d0 + j) * 72 + 2 * kp] = pr;
        }
      }
      __syncthreads();

      // S = Q K^T (16 queries x 64 keys per wave)
      f32x4 s[4];
#pragma unroll
      for (int nt = 0; nt < 4; ++nt) {
        s[nt] = {0.f, 0.f, 0.f, 0.f};
#pragma unroll
        for (int ks = 0; ks < 4; ++ks) {
          bf16x8 kf = *(const bf16x8*)&Ks[(nt * 16 + l15) * 136 + ks * 32 + quad * 8];
          s[nt] = MFMA_BF16(qf[ks], kf, s[nt]);
        }
      }

      float sv[4][4];
#pragma unroll
      for (int nt = 0; nt < 4; ++nt) {
#pragma unroll
        for (int r = 0; r < 4; ++r) {
          float v = s[nt][r] * scale;
          const int key = k0 + nt * 16 + l15;
          const int qq = q0 + wave * 16 + quad * 4 + r;
          if (key > qq) v = -1e9f;
          sv[nt][r] = v;
        }
      }

      // online softmax per query row (row lives across 16 lanes of a quad)
#pragma unroll
      for (int r = 0; r < 4; ++r) {
        float rmax = fmaxf(fmaxf(sv[0][r], sv[1][r]), fmaxf(sv[2][r], sv[3][r]));
#pragma unroll
        for (int off = 1; off < 16; off <<= 1) rmax = fmaxf(rmax, __shfl_xor(rmax, off));
        const float mnew = fmaxf(m_r[r], rmax);
        const float alpha = __expf(m_r[r] - mnew);
        float psum = 0.f;
#pragma unroll
        for (int nt = 0; nt < 4; ++nt) {
          const float p = __expf(sv[nt][r] - mnew);
          psum += p;
          Ps[wave * 1152 + (quad * 4 + r) * 72 + nt * 16 + l15] = (bf16)p;
        }
#pragma unroll
        for (int off = 1; off < 16; off <<= 1) psum += __shfl_xor(psum, off);
        l_r[r] = l_r[r] * alpha + psum;
        m_r[r] = mnew;
#pragma unroll
        for (int nt2 = 0; nt2 < 8; ++nt2) o[nt2][r] *= alpha;
      }

      // drain same-wave P writes before cross-lane reads
      asm volatile("s_waitcnt lgkmcnt(0)" ::: "memory");

      // O += P V
#pragma unroll
      for (int ks2 = 0; ks2 < 2; ++ks2) {
        bf16x8 pf = *(const bf16x8*)&Ps[wave * 1152 + l15 * 72 + ks2 * 32 + quad * 8];
#pragma unroll
        for (int nt2 = 0; nt2 < 8; ++nt2) {
          bf16x8 vf = *(const bf16x8*)&Vt[(nt2 * 16 + l15) * 72 + ks2 * 32 + quad * 8];
          o[nt2] = MFMA_BF16(pf, vf, o[nt2]);
        }
      }
    }

#pragma unroll
    for (int nt2 = 0; nt2 < 8; ++nt2) {
#pragma unroll
      for (int r = 0; r < 4; ++r) {
        const int qq = q0 + wave * 16 + quad * 4 + r;
        const int dd = nt2 * 16 + l15;
        O[base + (size_t)qq * 2048 + dd] = (bf16)(o[nt2][r] / l_r[r]);
      }
    }
  }
}

// ---------------------------------------------------------------------------
extern "C" void kernel_launch(void* const* d_in, const int* in_sizes, int n_in,
                              void* d_out, int out_size, void* d_ws, size_t ws_size,
                              hipStream_t stream) {
  const void* x_raw = d_in[0];
  const void* cos_raw = d_in[1];
  const void* sin_raw = d_in[2];
  // d_in[3] = mask — causal, applied analytically in flash_attn
  const void* g1_raw = d_in[4];
  const void* g2_raw = d_in[5];
  const void* W_raw[7] = {d_in[6], d_in[7], d_in[8], d_in[9], d_in[10], d_in[11], d_in[12]};

  char* ws = (char*)d_ws;
  const size_t MB = 1048576ull;
  int* flag = (int*)ws;
  bf16* g1c = (bf16*)(ws + 4096);
  bf16* g2c = (bf16*)(ws + 12288);
  bf16* cosc = (bf16*)(ws + 65536);          // 512KB
  bf16* sinc = (bf16*)(ws + 655360);         // 512KB
  bf16* xc   = (bf16*)(ws + 2 * MB);         // 16MB  [2,18)
  bf16* wslot= (bf16*)(ws + 18 * MB);        // 23MB  [18,41)
  bf16* hbuf = (bf16*)(ws + 41 * MB);        // 16MB  [41,57)
  bf16* qbuf = (bf16*)(ws + 57 * MB);        // 16MB  [57,73)
  bf16* kbuf = (bf16*)(ws + 73 * MB);        // 16MB  [73,89)
  bf16* vbuf = (bf16*)(ws + 89 * MB);        // 16MB  [89,105)
  bf16* abuf = (bf16*)(ws + 105 * MB);       // 16MB  [105,121)
  float* x1  = (float*)(ws + 57 * MB);       // 32MB over q,k (dead after flash)
  bf16* h2   = (bf16*)(ws + 41 * MB);        // over h (dead after V gemm)
  bf16* ubuf = (bf16*)(ws + 89 * MB);        // 43MB over v,attn [89,132)

  const int M = 4096;  // B*T
  dim3 blk(256);

  detect_dtype<<<1, 64, 0, stream>>>((const unsigned int*)x_raw, flag);

  convert_in<<<4096, blk, 0, stream>>>(x_raw, xc, flag);
  convert_in<<<128, blk, 0, stream>>>(cos_raw, cosc, flag);
  convert_in<<<128, blk, 0, stream>>>(sin_raw, sinc, flag);
  convert_in<<<1, blk, 0, stream>>>(g1_raw, g1c, flag);
  convert_in<<<1, blk, 0, stream>>>(g2_raw, g2c, flag);

  rmsnorm_bf16<<<M, blk, 0, stream>>>(xc, g1c, hbuf);

  convert_in<<<2048, blk, 0, stream>>>(W_raw[0], wslot, flag);
  gemm_bt<0><<<dim3(16, 32), blk, 0, stream>>>(hbuf, wslot, qbuf, nullptr, nullptr, nullptr, nullptr, nullptr, M, 2048, 2048);
  convert_in<<<2048, blk, 0, stream>>>(W_raw[1], wslot, flag);
  gemm_bt<0><<<dim3(16, 32), blk, 0, stream>>>(hbuf, wslot, kbuf, nullptr, nullptr, nullptr, nullptr, nullptr, M, 2048, 2048);
  convert_in<<<2048, blk, 0, stream>>>(W_raw[2], wslot, flag);
  gemm_bt<0><<<dim3(16, 32), blk, 0, stream>>>(hbuf, wslot, vbuf, nullptr, nullptr, nullptr, nullptr, nullptr, M, 2048, 2048);

  rope_k<<<M / 2, blk, 0, stream>>>(qbuf, kbuf, cosc, sinc);
  flash_attn<<<dim3(16, 32), blk, 0, stream>>>(qbuf, kbuf, vbuf, abuf);

  convert_in<<<2048, blk, 0, stream>>>(W_raw[3], wslot, flag);
  gemm_bt<1><<<dim3(16, 32), blk, 0, stream>>>(abuf, wslot, nullptr, x1, xc, nullptr, nullptr, nullptr, M, 2048, 2048);

  rmsnorm_f32<<<M, blk, 0, stream>>>(x1, g2c, h2);

  convert_in<<<5504, blk, 0, stream>>>(W_raw[4], wslot, flag);
  gemm_bt<2><<<dim3(43, 32), blk, 0, stream>>>(h2, wslot, ubuf, nullptr, nullptr, nullptr, nullptr, nullptr, M, 5504, 2048);
  convert_in<<<5504, blk, 0, stream>>>(W_raw[5], wslot, flag);
  gemm_bt<3><<<dim3(43, 32), blk, 0, stream>>>(h2, wslot, ubuf, nullptr, nullptr, nullptr, ubuf, nullptr, M, 5504, 2048);
  convert_in<<<5504, blk, 0, stream>>>(W_raw[6], wslot, flag);
  gemm_bt<4><<<dim3(16, 32), blk, 0, stream>>>(ubuf, wslot, (bf16*)d_out, (float*)d_out, nullptr, x1, nullptr, flag, M, 2048, 5504);
}

// Round 5
// 1045.483 us; speedup vs baseline: 1.2164x; 1.0707x over previous
//
#include <hip/hip_runtime.h>

// TransformerBlock on MI355X (gfx950). B=2 T=2048 D_MODEL=2048 H=16 HD=128 D_FF=5504.
// Round 5: GEMM K-loop double-buffered LDS; staging of tile k+1 issued after the
// barrier so global_load_lds overlaps MFMA on tile k. One barrier per K-step.

using bf16 = __bf16;
typedef __bf16 bf16x2 __attribute__((ext_vector_type(2)));
typedef __bf16 bf16x8 __attribute__((ext_vector_type(8)));
typedef float f32x4 __attribute__((ext_vector_type(4)));

#define MFMA_BF16(a, b, c) __builtin_amdgcn_mfma_f32_16x16x32_bf16((a), (b), (c), 0, 0, 0)

__device__ __forceinline__ void gld_lds16(const void* g, void* l) {
  // async global->LDS; LDS dst = wave-uniform base + lane*16 (HW rule).
  __builtin_amdgcn_global_load_lds((const __attribute__((address_space(1))) void*)g,
                                   (__attribute__((address_space(3))) void*)l,
                                   16, 0, 0);
}

// ---------------------------------------------------------------------------
// Detect input dtype (fp32 vs bf16) from x's first 64 words. flag=1 -> bf16.
// ---------------------------------------------------------------------------
__global__ void detect_dtype(const unsigned int* __restrict__ X, int* __restrict__ flag) {
  const int tid = threadIdx.x;  // 64 threads = 1 wave
  const unsigned int w = X[tid];
  const unsigned int e_lo = (w >> 7) & 0xFF;
  const unsigned int e_hi = (w >> 23) & 0xFF;
  const bool sane = (e_lo >= 97u && e_lo <= 157u) && (e_hi >= 97u && e_hi <= 157u);
  const unsigned long long m = __ballot(sane);
  if (tid == 0) *flag = (__popcll(m) > 48) ? 1 : 0;
}

__global__ __launch_bounds__(256) void convert_in(const void* __restrict__ src,
                                                  bf16* __restrict__ dst,
                                                  const int* __restrict__ flag) {
  const size_t i = ((size_t)blockIdx.x * 256 + threadIdx.x) * 8;
  if (*flag) {
    *(bf16x8*)(dst + i) = *(const bf16x8*)((const bf16*)src + i);
  } else {
    const float* s = (const float*)src;
    float4 a = *(const float4*)(s + i);
    float4 b = *(const float4*)(s + i + 4);
    bf16x8 o;
    o[0] = (bf16)a.x; o[1] = (bf16)a.y; o[2] = (bf16)a.z; o[3] = (bf16)a.w;
    o[4] = (bf16)b.x; o[5] = (bf16)b.y; o[6] = (bf16)b.z; o[7] = (bf16)b.w;
    *(bf16x8*)(dst + i) = o;
  }
}

// ---------------------------------------------------------------------------
// RMSNorm kernels (fp32 math).
// ---------------------------------------------------------------------------
__global__ __launch_bounds__(256) void rmsnorm_bf16(const bf16* __restrict__ X,
                                                    const bf16* __restrict__ g,
                                                    bf16* __restrict__ Hout) {
  const int row = blockIdx.x, tid = threadIdx.x;
  const size_t off = (size_t)row * 2048 + tid * 8;
  bf16x8 x8 = *(const bf16x8*)(X + off);
  float v[8];
  float s = 0.f;
#pragma unroll
  for (int j = 0; j < 8; ++j) { v[j] = (float)x8[j]; s += v[j] * v[j]; }
#pragma unroll
  for (int o = 32; o; o >>= 1) s += __shfl_xor(s, o);
  __shared__ float red[4];
  if ((tid & 63) == 0) red[tid >> 6] = s;
  __syncthreads();
  const float tot = red[0] + red[1] + red[2] + red[3];
  const float inv = 1.f / (sqrtf(tot * (1.f / 2048.f)) + 1e-8f);
  bf16x8 g8 = *(const bf16x8*)(g + tid * 8);
  bf16x8 o8;
#pragma unroll
  for (int j = 0; j < 8; ++j) o8[j] = (bf16)((float)g8[j] * v[j] * inv);
  *(bf16x8*)(Hout + off) = o8;
}

__global__ __launch_bounds__(256) void rmsnorm_f32(const float* __restrict__ X,
                                                   const bf16* __restrict__ g,
                                                   bf16* __restrict__ Hout) {
  const int row = blockIdx.x, tid = threadIdx.x;
  const size_t off = (size_t)row * 2048 + tid * 8;
  float4 a0 = *(const float4*)(X + off);
  float4 a1 = *(const float4*)(X + off + 4);
  float v[8] = {a0.x, a0.y, a0.z, a0.w, a1.x, a1.y, a1.z, a1.w};
  float s = 0.f;
#pragma unroll
  for (int j = 0; j < 8; ++j) s += v[j] * v[j];
#pragma unroll
  for (int o = 32; o; o >>= 1) s += __shfl_xor(s, o);
  __shared__ float red[4];
  if ((tid & 63) == 0) red[tid >> 6] = s;
  __syncthreads();
  const float tot = red[0] + red[1] + red[2] + red[3];
  const float inv = 1.f / (sqrtf(tot * (1.f / 2048.f)) + 1e-8f);
  bf16x8 g8 = *(const bf16x8*)(g + tid * 8);
  bf16x8 o8;
#pragma unroll
  for (int j = 0; j < 8; ++j) o8[j] = (bf16)((float)g8[j] * v[j] * inv);
  *(bf16x8*)(Hout + off) = o8;
}

// ---------------------------------------------------------------------------
// RoPE in-place on Q and K.
// ---------------------------------------------------------------------------
__global__ __launch_bounds__(256) void rope_k(bf16* __restrict__ Q, bf16* __restrict__ Kg,
                                              const bf16* __restrict__ cosb,
                                              const bf16* __restrict__ sinb) {
  const int tid = threadIdx.x;
  const int rr = tid >> 7;
  const int c = tid & 127;
  const int bt = blockIdx.x * 2 + rr;
  const int t = bt & 2047;
  const int h = c >> 3;
  const int d0 = (c & 7) * 8;
  const size_t row = (size_t)bt * 2048;
  const int i0 = h * 128 + d0;
  bf16x8 c0 = *(const bf16x8*)(cosb + t * 128 + d0);
  bf16x8 c1 = *(const bf16x8*)(cosb + t * 128 + d0 + 64);
  bf16x8 s0 = *(const bf16x8*)(sinb + t * 128 + d0);
  bf16x8 s1 = *(const bf16x8*)(sinb + t * 128 + d0 + 64);
  bf16x8 qa = *(const bf16x8*)(Q + row + i0);
  bf16x8 qb = *(const bf16x8*)(Q + row + i0 + 64);
  bf16x8 ka = *(const bf16x8*)(Kg + row + i0);
  bf16x8 kb = *(const bf16x8*)(Kg + row + i0 + 64);
  bf16x8 qo0, qo1, ko0, ko1;
#pragma unroll
  for (int j = 0; j < 8; ++j) {
    float cj0 = (float)c0[j], cj1 = (float)c1[j];
    float sj0 = (float)s0[j], sj1 = (float)s1[j];
    float qaj = (float)qa[j], qbj = (float)qb[j];
    float kaj = (float)ka[j], kbj = (float)kb[j];
    qo0[j] = (bf16)(qaj * cj0 - qbj * sj0);
    qo1[j] = (bf16)(qbj * cj1 + qaj * sj1);
    ko0[j] = (bf16)(kaj * cj0 - kbj * sj0);
    ko1[j] = (bf16)(kbj * cj1 + kaj * sj1);
  }
  *(bf16x8*)(Q + row + i0) = qo0;
  *(bf16x8*)(Q + row + i0 + 64) = qo1;
  *(bf16x8*)(Kg + row + i0) = ko0;
  *(bf16x8*)(Kg + row + i0 + 64) = ko1;
}

// ---------------------------------------------------------------------------
// GEMM C = A(MxK) * W(NxK)^T, bf16 MFMA 16x16x32, 128x128 tile, 4 waves 2x2.
// Double-buffered LDS: stage(k+1) issued after the barrier, overlapping MFMA(k).
// EPI: 0 bf16; 1 fp32 = v + bf16 res; 2 silu->bf16; 3 v*mulb->bf16;
//      4 fp32 res + v -> d_out (dtype per oflag).
// ---------------------------------------------------------------------------
template <int EPI>
__global__ __launch_bounds__(256) void gemm_bt(const bf16* __restrict__ A,
                                               const bf16* __restrict__ W,
                                               bf16* __restrict__ Cb, float* __restrict__ Cf,
                                               const bf16* __restrict__ resb,
                                               const float* __restrict__ resf,
                                               const bf16* __restrict__ mulb,
                                               const int* __restrict__ oflag,
                                               int M, int N, int K) {
  __shared__ bf16 As[2][128 * 32];
  __shared__ bf16 Ws[2][128 * 32];
  const int tid = threadIdx.x;
  const int wave = tid >> 6, lane = tid & 63;
  const int quad = lane >> 4, l15 = lane & 15;
  const int wm = wave >> 1, wn = wave & 1;
  const int m0 = blockIdx.y * 128, n0 = blockIdx.x * 128;

  f32x4 acc[4][4];
#pragma unroll
  for (int i = 0; i < 4; ++i)
#pragma unroll
    for (int j = 0; j < 4; ++j) acc[i][j] = {0.f, 0.f, 0.f, 0.f};

  const int srow = lane >> 2;       // 0..15
  const int skk = (lane & 3) * 8;   // 0,8,16,24
  const bf16* Ab = A + (size_t)m0 * K;
  const bf16* Wb = W + (size_t)n0 * K;

  // stage one 128x32 K-slice of A and W into buffer `buf` (async, 16B/lane)
  auto stage = [&](int buf, int kb) {
    const int k0 = kb << 5;
#pragma unroll
    for (int c = 0; c < 2; ++c) {
      const int r = (wave * 2 + c) * 16 + srow;
      gld_lds16(Ab + (size_t)r * K + k0 + skk, (char*)As[buf] + (wave * 2 + c) * 1024);
      gld_lds16(Wb + (size_t)r * K + k0 + skk, (char*)Ws[buf] + (wave * 2 + c) * 1024);
    }
  };
  // ds_read frags from buffer `buf` and run 16 MFMAs
  auto compute = [&](int buf) {
    bf16x8 af[4], wf[4];
#pragma unroll
    for (int mt = 0; mt < 4; ++mt)
      af[mt] = *(const bf16x8*)&As[buf][(wm * 64 + mt * 16 + l15) * 32 + quad * 8];
#pragma unroll
    for (int nt = 0; nt < 4; ++nt)
      wf[nt] = *(const bf16x8*)&Ws[buf][(wn * 64 + nt * 16 + l15) * 32 + quad * 8];
#pragma unroll
    for (int mt = 0; mt < 4; ++mt)
#pragma unroll
      for (int nt = 0; nt < 4; ++nt)
        acc[mt][nt] = MFMA_BF16(af[mt], wf[nt], acc[mt][nt]);
  };

  const int nk = K >> 5;  // always even here (64 or 172)
  stage(0, 0);
  for (int kb = 0; kb < nk; kb += 2) {
    __syncthreads();                     // buf0 loads drained (vmcnt0) + reads of buf0 done
    if (kb + 1 < nk) stage(1, kb + 1);   // overlaps compute(buf0)
    compute(0);
    __syncthreads();                     // buf1 loads drained + reads of buf1 done
    if (kb + 2 < nk) stage(0, kb + 2);   // overlaps compute(buf1)
    compute(1);
  }

  const int obf = (EPI == 4 && oflag) ? *oflag : 0;
#pragma unroll
  for (int mt = 0; mt < 4; ++mt) {
#pragma unroll
    for (int nt = 0; nt < 4; ++nt) {
#pragma unroll
      for (int r = 0; r < 4; ++r) {
        const int row = m0 + wm * 64 + mt * 16 + quad * 4 + r;
        const int col = n0 + wn * 64 + nt * 16 + l15;
        const size_t idx = (size_t)row * N + col;
        const float v = acc[mt][nt][r];
        if constexpr (EPI == 0) {
          Cb[idx] = (bf16)v;
        } else if constexpr (EPI == 1) {
          Cf[idx] = v + (float)resb[idx];
        } else if constexpr (EPI == 2) {
          Cb[idx] = (bf16)(v / (1.f + __expf(-v)));   // silu
        } else if constexpr (EPI == 3) {
          Cb[idx] = (bf16)((float)mulb[idx] * v);
        } else {  // EPI == 4: final output, dtype per flag
          const float rres = resf[idx] + v;
          if (obf) Cb[idx] = (bf16)rres;
          else     Cf[idx] = rres;
        }
      }
    }
  }
}

// ---------------------------------------------------------------------------
// Flash attention (causal). Grid (16, B*H); block p handles q-tiles p and 31-p.
// Padded LDS rows (Ks 136, Vt/Ps 72) -> no bank conflicts.
// ---------------------------------------------------------------------------
__global__ __launch_bounds__(256) void flash_attn(const bf16* __restrict__ Q,
                                                  const bf16* __restrict__ Kg,
                                                  const bf16* __restrict__ Vg,
                                                  bf16* __restrict__ O) {
  __shared__ bf16 Ks[64 * 136];
  __shared__ bf16 Vt[128 * 72];
  __shared__ bf16 Ps[4 * 16 * 72];
  const int tid = threadIdx.x;
  const int wave = tid >> 6, lane = tid & 63;
  const int quad = lane >> 4, l15 = lane & 15;
  const int bh = blockIdx.y;
  const int b = bh >> 4, h = bh & 15;
  const size_t base = (size_t)b * 2048 * 2048 + h * 128;
  const float scale = 0.08838834764831845f;  // 1/sqrt(128)

#pragma unroll 1
  for (int half = 0; half < 2; ++half) {
    const int qt = half ? (31 - blockIdx.x) : blockIdx.x;
    const int q0 = qt * 64;

    bf16x8 qf[4];
    {
      const bf16* qrow = Q + base + (size_t)(q0 + wave * 16 + l15) * 2048;
#pragma unroll
      for (int ks = 0; ks < 4; ++ks) qf[ks] = *(const bf16x8*)(qrow + ks * 32 + quad * 8);
    }

    f32x4 o[8];
#pragma unroll
    for (int i = 0; i < 8; ++i) o[i] = {0.f, 0.f, 0.f, 0.f};
    float m_r[4] = {-1e30f, -1e30f, -1e30f, -1e30f};
    float l_r[4] = {0.f, 0.f, 0.f, 0.f};

    for (int kb = 0; kb <= qt; ++kb) {
      const int k0 = kb * 64;
      __syncthreads();
#pragma unroll
      for (int c = 0; c < 4; ++c) {
        const int ch = tid + 256 * c;
        const int row = ch >> 4;
        const int dd = (ch & 15) * 8;
        *(bf16x8*)&Ks[row * 136 + dd] =
            *(const bf16x8*)(Kg + base + (size_t)(k0 + row) * 2048 + dd);
      }
#pragma unroll
      for (int c = 0; c < 2; ++c) {
        const int tau = tid + 256 * c;
        const int kp = tau & 31;
        const int d0 = (tau >> 5) * 8;
        bf16x8 va = *(const bf16x8*)(Vg + base + (size_t)(k0 + 2 * kp) * 2048 + d0);
        bf16x8 vb = *(const bf16x8*)(Vg + base + (size_t)(k0 + 2 * kp + 1) * 2048 + d0);
#pragma unroll
        for (int j = 0; j < 8; ++j) {
          bf16x2 pr = {va[j], vb[j]};
          *(bf16x2*)&Vt[(d0 + j) * 72 + 2 * kp] = pr;
        }
      }
      __syncthreads();

      f32x4 s[4];
#pragma unroll
      for (int nt = 0; nt < 4; ++nt) {
        s[nt] = {0.f, 0.f, 0.f, 0.f};
#pragma unroll
        for (int ks = 0; ks < 4; ++ks) {
          bf16x8 kf = *(const bf16x8*)&Ks[(nt * 16 + l15) * 136 + ks * 32 + quad * 8];
          s[nt] = MFMA_BF16(qf[ks], kf, s[nt]);
        }
      }

      float sv[4][4];
#pragma unroll
      for (int nt = 0; nt < 4; ++nt) {
#pragma unroll
        for (int r = 0; r < 4; ++r) {
          float v = s[nt][r] * scale;
          const int key = k0 + nt * 16 + l15;
          const int qq = q0 + wave * 16 + quad * 4 + r;
          if (key > qq) v = -1e9f;
          sv[nt][r] = v;
        }
      }

#pragma unroll
      for (int r = 0; r < 4; ++r) {
        float rmax = fmaxf(fmaxf(sv[0][r], sv[1][r]), fmaxf(sv[2][r], sv[3][r]));
#pragma unroll
        for (int off = 1; off < 16; off <<= 1) rmax = fmaxf(rmax, __shfl_xor(rmax, off));
        const float mnew = fmaxf(m_r[r], rmax);
        const float alpha = __expf(m_r[r] - mnew);
        float psum = 0.f;
#pragma unroll
        for (int nt = 0; nt < 4; ++nt) {
          const float p = __expf(sv[nt][r] - mnew);
          psum += p;
          Ps[wave * 1152 + (quad * 4 + r) * 72 + nt * 16 + l15] = (bf16)p;
        }
#pragma unroll
        for (int off = 1; off < 16; off <<= 1) psum += __shfl_xor(psum, off);
        l_r[r] = l_r[r] * alpha + psum;
        m_r[r] = mnew;
#pragma unroll
        for (int nt2 = 0; nt2 < 8; ++nt2) o[nt2][r] *= alpha;
      }

      asm volatile("s_waitcnt lgkmcnt(0)" ::: "memory");

#pragma unroll
      for (int ks2 = 0; ks2 < 2; ++ks2) {
        bf16x8 pf = *(const bf16x8*)&Ps[wave * 1152 + l15 * 72 + ks2 * 32 + quad * 8];
#pragma unroll
        for (int nt2 = 0; nt2 < 8; ++nt2) {
          bf16x8 vf = *(const bf16x8*)&Vt[(nt2 * 16 + l15) * 72 + ks2 * 32 + quad * 8];
          o[nt2] = MFMA_BF16(pf, vf, o[nt2]);
        }
      }
    }

#pragma unroll
    for (int nt2 = 0; nt2 < 8; ++nt2) {
#pragma unroll
      for (int r = 0; r < 4; ++r) {
        const int qq = q0 + wave * 16 + quad * 4 + r;
        const int dd = nt2 * 16 + l15;
        O[base + (size_t)qq * 2048 + dd] = (bf16)(o[nt2][r] / l_r[r]);
      }
    }
  }
}

// ---------------------------------------------------------------------------
extern "C" void kernel_launch(void* const* d_in, const int* in_sizes, int n_in,
                              void* d_out, int out_size, void* d_ws, size_t ws_size,
                              hipStream_t stream) {
  const void* x_raw = d_in[0];
  const void* cos_raw = d_in[1];
  const void* sin_raw = d_in[2];
  // d_in[3] = mask — causal, applied analytically in flash_attn
  const void* g1_raw = d_in[4];
  const void* g2_raw = d_in[5];
  const void* W_raw[7] = {d_in[6], d_in[7], d_in[8], d_in[9], d_in[10], d_in[11], d_in[12]};

  char* ws = (char*)d_ws;
  const size_t MB = 1048576ull;
  int* flag = (int*)ws;
  bf16* g1c = (bf16*)(ws + 4096);
  bf16* g2c = (bf16*)(ws + 12288);
  bf16* cosc = (bf16*)(ws + 65536);          // 512KB
  bf16* sinc = (bf16*)(ws + 655360);         // 512KB
  bf16* xc   = (bf16*)(ws + 2 * MB);         // 16MB  [2,18)
  bf16* wslot= (bf16*)(ws + 18 * MB);        // 23MB  [18,41)
  bf16* hbuf = (bf16*)(ws + 41 * MB);        // 16MB  [41,57)
  bf16* qbuf = (bf16*)(ws + 57 * MB);        // 16MB  [57,73)
  bf16* kbuf = (bf16*)(ws + 73 * MB);        // 16MB  [73,89)
  bf16* vbuf = (bf16*)(ws + 89 * MB);        // 16MB  [89,105)
  bf16* abuf = (bf16*)(ws + 105 * MB);       // 16MB  [105,121)
  float* x1  = (float*)(ws + 57 * MB);       // 32MB over q,k (dead after flash)
  bf16* h2   = (bf16*)(ws + 41 * MB);        // over h (dead after V gemm)
  bf16* ubuf = (bf16*)(ws + 89 * MB);        // 43MB over v,attn [89,132)

  const int M = 4096;  // B*T
  dim3 blk(256);

  detect_dtype<<<1, 64, 0, stream>>>((const unsigned int*)x_raw, flag);

  convert_in<<<4096, blk, 0, stream>>>(x_raw, xc, flag);
  convert_in<<<128, blk, 0, stream>>>(cos_raw, cosc, flag);
  convert_in<<<128, blk, 0, stream>>>(sin_raw, sinc, flag);
  convert_in<<<1, blk, 0, stream>>>(g1_raw, g1c, flag);
  convert_in<<<1, blk, 0, stream>>>(g2_raw, g2c, flag);

  rmsnorm_bf16<<<M, blk, 0, stream>>>(xc, g1c, hbuf);

  convert_in<<<2048, blk, 0, stream>>>(W_raw[0], wslot, flag);
  gemm_bt<0><<<dim3(16, 32), blk, 0, stream>>>(hbuf, wslot, qbuf, nullptr, nullptr, nullptr, nullptr, nullptr, M, 2048, 2048);
  convert_in<<<2048, blk, 0, stream>>>(W_raw[1], wslot, flag);
  gemm_bt<0><<<dim3(16, 32), blk, 0, stream>>>(hbuf, wslot, kbuf, nullptr, nullptr, nullptr, nullptr, nullptr, M, 2048, 2048);
  convert_in<<<2048, blk, 0, stream>>>(W_raw[2], wslot, flag);
  gemm_bt<0><<<dim3(16, 32), blk, 0, stream>>>(hbuf, wslot, vbuf, nullptr, nullptr, nullptr, nullptr, nullptr, M, 2048, 2048);

  rope_k<<<M / 2, blk, 0, stream>>>(qbuf, kbuf, cosc, sinc);
  flash_attn<<<dim3(16, 32), blk, 0, stream>>>(qbuf, kbuf, vbuf, abuf);

  convert_in<<<2048, blk, 0, stream>>>(W_raw[3], wslot, flag);
  gemm_bt<1><<<dim3(16, 32), blk, 0, stream>>>(abuf, wslot, nullptr, x1, xc, nullptr, nullptr, nullptr, M, 2048, 2048);

  rmsnorm_f32<<<M, blk, 0, stream>>>(x1, g2c, h2);

  convert_in<<<5504, blk, 0, stream>>>(W_raw[4], wslot, flag);
  gemm_bt<2><<<dim3(43, 32), blk, 0, stream>>>(h2, wslot, ubuf, nullptr, nullptr, nullptr, nullptr, nullptr, M, 5504, 2048);
  convert_in<<<5504, blk, 0, stream>>>(W_raw[5], wslot, flag);
  gemm_bt<3><<<dim3(43, 32), blk, 0, stream>>>(h2, wslot, ubuf, nullptr, nullptr, nullptr, ubuf, nullptr, M, 5504, 2048);
  convert_in<<<5504, blk, 0, stream>>>(W_raw[6], wslot, flag);
  gemm_bt<4><<<dim3(16, 32), blk, 0, stream>>>(ubuf, wslot, (bf16*)d_out, (float*)d_out, nullptr, x1, nullptr, flag, M, 2048, 5504);
}